// Round 1
// baseline (7170.071 us; speedup 1.0000x reference)
//
#include <hip/hip_runtime.h>
#include <cstdint>
#include <cstddef>

// LSTM cell, fused: g = [X|Hprev] @ [Wih|Whh]^T + b, gates -> (h_new, c_new).
// Round 0: fp32 vector baseline (no MFMA yet), fully fused epilogue.
// Tiling: block = 64 rows (M) x 64 h-cols x 4 gates; 256 threads (16x16),
// each thread: 4 rows x 4 cols x 4 gates = 64 accumulators.
// LDS k-major with +1 pad: staging writes and compute reads are conflict-free.

#define BM 64
#define BH 64
#define BK 32

__device__ __forceinline__ float sigmoidf_(float x) {
    return 1.0f / (1.0f + __expf(-x));
}
__device__ __forceinline__ float tanh_fast(float x) {
    // tanh(x) = 2*sigmoid(2x) - 1 ; saturates correctly for large |x|
    return 2.0f / (1.0f + __expf(-2.0f * x)) - 1.0f;
}

__global__ __launch_bounds__(256)
void lstm_fused_fp32(const float* __restrict__ X,      // [B,1024]
                     const float* __restrict__ Hprev,  // [B,1024]
                     const float* __restrict__ Cprev,  // [B,1024]
                     const float* __restrict__ Wih,    // [4096,1024]
                     const float* __restrict__ Whh,    // [4096,1024]
                     const float* __restrict__ bih,    // [4096]
                     const float* __restrict__ bhh,    // [4096]
                     float* __restrict__ Out,          // [2*B*1024]: h_new then c_new
                     int Btot)
{
    __shared__ float As[BK][BM + 1];        // [k][m], pad +1: stage writes k-across-lanes hit distinct banks
    __shared__ float Bs[4][BK][BH + 1];     // [gate][k][h]

    const int tx = threadIdx.x;             // 0..15 -> h
    const int ty = threadIdx.y;             // 0..15 -> m
    const int tid = ty * 16 + tx;
    const int m0 = blockIdx.y * BM;
    const int h0 = blockIdx.x * BH;

    float acc[4][4][4];                     // [gate][mi][hj]
    #pragma unroll
    for (int g = 0; g < 4; ++g)
        #pragma unroll
        for (int i = 0; i < 4; ++i)
            #pragma unroll
            for (int j = 0; j < 4; ++j)
                acc[g][i][j] = 0.0f;

    const int kl = tid & 31;                // k within tile (lanes 0..31 -> coalesced 128B row reads)
    const int rb = tid >> 5;                // 0..7 row base

    for (int phase = 0; phase < 2; ++phase) {
        const float* __restrict__ Ap = phase ? Hprev : X;
        const float* __restrict__ Wp = phase ? Whh : Wih;

        for (int k0 = 0; k0 < 1024; k0 += BK) {
            // ---- stage A tile: 64 rows x 32 k ----
            #pragma unroll
            for (int i = 0; i < 8; ++i) {
                int m = rb + i * 8;
                As[kl][m] = Ap[(size_t)(m0 + m) * 1024 + (k0 + kl)];
            }
            // ---- stage B tiles: 4 gates x 64 cols x 32 k ----
            #pragma unroll
            for (int g = 0; g < 4; ++g) {
                #pragma unroll
                for (int i = 0; i < 8; ++i) {
                    int j = rb + i * 8;
                    Bs[g][kl][j] = Wp[(size_t)(g * 1024 + h0 + j) * 1024 + (k0 + kl)];
                }
            }
            __syncthreads();

            // ---- compute: 64 FMA per k-step per thread ----
            #pragma unroll 8
            for (int kk = 0; kk < BK; ++kk) {
                float a0 = As[kk][ty * 4 + 0];
                float a1 = As[kk][ty * 4 + 1];
                float a2 = As[kk][ty * 4 + 2];
                float a3 = As[kk][ty * 4 + 3];
                #pragma unroll
                for (int g = 0; g < 4; ++g) {
                    float b0 = Bs[g][kk][tx * 4 + 0];
                    float b1 = Bs[g][kk][tx * 4 + 1];
                    float b2 = Bs[g][kk][tx * 4 + 2];
                    float b3 = Bs[g][kk][tx * 4 + 3];
                    acc[g][0][0] += a0 * b0; acc[g][0][1] += a0 * b1;
                    acc[g][0][2] += a0 * b2; acc[g][0][3] += a0 * b3;
                    acc[g][1][0] += a1 * b0; acc[g][1][1] += a1 * b1;
                    acc[g][1][2] += a1 * b2; acc[g][1][3] += a1 * b3;
                    acc[g][2][0] += a2 * b0; acc[g][2][1] += a2 * b1;
                    acc[g][2][2] += a2 * b2; acc[g][2][3] += a2 * b3;
                    acc[g][3][0] += a3 * b0; acc[g][3][1] += a3 * b1;
                    acc[g][3][2] += a3 * b2; acc[g][3][3] += a3 * b3;
                }
            }
            __syncthreads();
        }
    }

    // ---- fused epilogue ----
    float bsum[4][4];
    #pragma unroll
    for (int g = 0; g < 4; ++g)
        #pragma unroll
        for (int hj = 0; hj < 4; ++hj) {
            int n = g * 1024 + h0 + tx * 4 + hj;
            bsum[g][hj] = bih[n] + bhh[n];
        }

    const size_t c_off = (size_t)Btot * 1024;   // h_new at [0, B*H), c_new after
    #pragma unroll
    for (int mi = 0; mi < 4; ++mi) {
        const int m = m0 + ty * 4 + mi;
        const size_t rowoff = (size_t)m * 1024 + h0 + tx * 4;
        const float4 cpv = *(const float4*)(Cprev + rowoff);
        const float cpa[4] = {cpv.x, cpv.y, cpv.z, cpv.w};
        float hn[4], cn[4];
        #pragma unroll
        for (int hj = 0; hj < 4; ++hj) {
            float gi = acc[0][mi][hj] + bsum[0][hj];
            float gf = acc[1][mi][hj] + bsum[1][hj];
            float gc = acc[2][mi][hj] + bsum[2][hj];
            float go = acc[3][mi][hj] + bsum[3][hj];
            float ig = sigmoidf_(gi);
            float fg = sigmoidf_(gf);
            float cd = tanh_fast(gc);
            float og = sigmoidf_(go);
            float c_new = cpa[hj] * fg + ig * cd;
            float h_new = tanh_fast(c_new) * og;
            cn[hj] = c_new;
            hn[hj] = h_new;
        }
        *(float4*)(Out + rowoff)         = make_float4(hn[0], hn[1], hn[2], hn[3]);
        *(float4*)(Out + c_off + rowoff) = make_float4(cn[0], cn[1], cn[2], cn[3]);
    }
}

extern "C" void kernel_launch(void* const* d_in, const int* in_sizes, int n_in,
                              void* d_out, int out_size, void* d_ws, size_t ws_size,
                              hipStream_t stream) {
    const float* X     = (const float*)d_in[0];
    const float* Hprev = (const float*)d_in[1];
    const float* Cprev = (const float*)d_in[2];
    const float* Wih   = (const float*)d_in[3];
    const float* Whh   = (const float*)d_in[4];
    const float* bih   = (const float*)d_in[5];
    const float* bhh   = (const float*)d_in[6];
    float* Out = (float*)d_out;

    const int Btot = in_sizes[0] / 1024;    // 16384
    dim3 grid(1024 / BH, Btot / BM);        // (16, 256)
    dim3 block(16, 16);
    hipLaunchKernelGGL(lstm_fused_fp32, grid, block, 0, stream,
                       X, Hprev, Cprev, Wih, Whh, bih, bhh, Out, Btot);
}

// Round 2
// 880.412 us; speedup vs baseline: 8.1440x; 8.1440x over previous
//
#include <hip/hip_runtime.h>
#include <cstdint>
#include <cstddef>

// LSTM cell fused via fp16 MFMA:
//   g = [X|Hprev] @ [Wih|Whh]^T + b  ->  gates -> (h_new, c_new)
// GEMM: M=16384 (batch), N=4096 (4 gates x 1024 h), K=2048, NT layout.
// Block: 256 thr / 4 waves; tile 128m x 256n (64 h-cols x 4 gates), BK=32.
// Wave w owns h in [16w,16w+16) across ALL 4 gates -> epilogue is lane-local.
// fp32->fp16 convert inline during staging; raw-float4 prefetch of tile k+1
// issued before the MFMA block so global latency hides under MFMA.
// LDS rows padded to 40 halves (80B): b128 frag reads <=2-way conflict (free).

typedef _Float16 half8 __attribute__((ext_vector_type(8)));
typedef float f32x4 __attribute__((ext_vector_type(4)));

#define BM 128
#define BHC 64            // h-cols per block (N-tile = 4*BHC = 256)
#define BK 32
#define NTILES 64         // 2048 / 32

__device__ __forceinline__ float sigmoidf_(float x) { return 1.0f / (1.0f + __expf(-x)); }
__device__ __forceinline__ float tanh_fast(float x) { return 2.0f / (1.0f + __expf(-2.0f * x)) - 1.0f; }

__device__ __forceinline__ half8 pack8(float4 a, float4 b) {
    half8 h;
    h[0] = (_Float16)a.x; h[1] = (_Float16)a.y; h[2] = (_Float16)a.z; h[3] = (_Float16)a.w;
    h[4] = (_Float16)b.x; h[5] = (_Float16)b.y; h[6] = (_Float16)b.z; h[7] = (_Float16)b.w;
    return h;
}

__global__ __launch_bounds__(256, 2)
void lstm_mfma_f16(const float* __restrict__ X,      // [B,1024]
                   const float* __restrict__ Hprev,  // [B,1024]
                   const float* __restrict__ Cprev,  // [B,1024]
                   const float* __restrict__ Wih,    // [4096,1024]
                   const float* __restrict__ Whh,    // [4096,1024]
                   const float* __restrict__ bih,    // [4096]
                   const float* __restrict__ bhh,    // [4096]
                   float* __restrict__ Out,          // h_new [B*1024] then c_new [B*1024]
                   int Btot, int mblocks)
{
    __shared__ alignas(16) _Float16 As[128][40];    // [m][k], 8-half pad
    __shared__ alignas(16) _Float16 Bs[256][40];    // [gate*64+h_local][k]

    const int tid  = threadIdx.x;
    const int w    = tid >> 6;        // wave 0..3
    const int lane = tid & 63;
    const int lr   = lane & 15;
    const int q    = lane >> 4;       // quadrant 0..3

    const int bx   = blockIdx.x;
    const int mblk = bx % mblocks;    // m fastest: W slices stay L2-hot, A stays L3-hot
    const int nblk = bx / mblocks;
    const int m0   = mblk * BM;
    const int hblk = nblk * BHC;

    // staging coords: thread -> (row = tid>>1, 16-wide k-chunk = tid&1)
    const int sr = tid >> 1;          // 0..127
    const int sc = tid & 1;

    f32x4 acc[8][4];
    #pragma unroll
    for (int mt = 0; mt < 8; ++mt)
        #pragma unroll
        for (int g = 0; g < 4; ++g)
            acc[mt][g] = (f32x4){0.0f, 0.0f, 0.0f, 0.0f};

    // prefetch registers: raw fp32 (convert deferred to store site)
    float4 pa[4];     // A row sr, 16 floats
    float4 pb0[4];    // B row sr
    float4 pb1[4];    // B row sr+128

    // B row -> global weight row: rb = gate*64 + h_local -> gate*1024 + hblk + h_local
    const int rb0 = sr;
    const int rb1 = sr + 128;
    const size_t wrow0 = (size_t)((rb0 >> 6) * 1024 + hblk + (rb0 & 63)) * 1024;
    const size_t wrow1 = (size_t)((rb1 >> 6) * 1024 + hblk + (rb1 & 63)) * 1024;
    const size_t arow  = (size_t)(m0 + sr) * 1024;

    auto stage_load = [&](int tile) {
        const int phase = tile >> 5;
        const int k0 = (tile & 31) * BK + sc * 16;
        const float* __restrict__ Ap = phase ? Hprev : X;
        const float* __restrict__ Wp = phase ? Whh : Wih;
        const float4* ap = (const float4*)(Ap + arow + k0);
        const float4* b0 = (const float4*)(Wp + wrow0 + k0);
        const float4* b1 = (const float4*)(Wp + wrow1 + k0);
        #pragma unroll
        for (int i = 0; i < 4; ++i) { pa[i] = ap[i]; pb0[i] = b0[i]; pb1[i] = b1[i]; }
    };

    stage_load(0);

    for (int tile = 0; tile < NTILES; ++tile) {
        __syncthreads();   // previous compute done reading LDS
        // convert + store staged tile
        *(half8*)&As[sr][sc * 16]           = pack8(pa[0], pa[1]);
        *(half8*)&As[sr][sc * 16 + 8]       = pack8(pa[2], pa[3]);
        *(half8*)&Bs[sr][sc * 16]           = pack8(pb0[0], pb0[1]);
        *(half8*)&Bs[sr][sc * 16 + 8]       = pack8(pb0[2], pb0[3]);
        *(half8*)&Bs[sr + 128][sc * 16]     = pack8(pb1[0], pb1[1]);
        *(half8*)&Bs[sr + 128][sc * 16 + 8] = pack8(pb1[2], pb1[3]);
        __syncthreads();

        if (tile + 1 < NTILES) stage_load(tile + 1);   // loads fly during MFMA block

        // B fragments: wave w, gate g -> rows g*64 + w*16 + lr
        half8 bf[4];
        #pragma unroll
        for (int g = 0; g < 4; ++g)
            bf[g] = *(const half8*)&Bs[g * 64 + w * 16 + lr][q * 8];

        #pragma unroll
        for (int mt = 0; mt < 8; ++mt) {
            half8 a = *(const half8*)&As[mt * 16 + lr][q * 8];
            #pragma unroll
            for (int g = 0; g < 4; ++g)
                acc[mt][g] = __builtin_amdgcn_mfma_f32_16x16x32_f16(a, bf[g], acc[mt][g], 0, 0, 0);
        }
    }

    // ---- fused epilogue: lane owns col h, 32 m-rows, all 4 gates ----
    const int h = hblk + w * 16 + lr;        // 0..1023
    float bs0 = bih[0 * 1024 + h] + bhh[0 * 1024 + h];
    float bs1 = bih[1 * 1024 + h] + bhh[1 * 1024 + h];
    float bs2 = bih[2 * 1024 + h] + bhh[2 * 1024 + h];
    float bs3 = bih[3 * 1024 + h] + bhh[3 * 1024 + h];
    const size_t c_off = (size_t)Btot * 1024;

    #pragma unroll
    for (int mt = 0; mt < 8; ++mt) {
        #pragma unroll
        for (int r = 0; r < 4; ++r) {
            const int m = m0 + mt * 16 + q * 4 + r;
            const size_t idx = (size_t)m * 1024 + h;
            float gi = acc[mt][0][r] + bs0;
            float gf = acc[mt][1][r] + bs1;
            float gc = acc[mt][2][r] + bs2;
            float go = acc[mt][3][r] + bs3;
            float ig = sigmoidf_(gi);
            float fg = sigmoidf_(gf);
            float cd = tanh_fast(gc);
            float og = sigmoidf_(go);
            float c_new = Cprev[idx] * fg + ig * cd;
            float h_new = tanh_fast(c_new) * og;
            Out[idx]         = h_new;
            Out[c_off + idx] = c_new;
        }
    }
}

extern "C" void kernel_launch(void* const* d_in, const int* in_sizes, int n_in,
                              void* d_out, int out_size, void* d_ws, size_t ws_size,
                              hipStream_t stream) {
    const float* X     = (const float*)d_in[0];
    const float* Hprev = (const float*)d_in[1];
    const float* Cprev = (const float*)d_in[2];
    const float* Wih   = (const float*)d_in[3];
    const float* Whh   = (const float*)d_in[4];
    const float* bih   = (const float*)d_in[5];
    const float* bhh   = (const float*)d_in[6];
    float* Out = (float*)d_out;

    const int Btot    = in_sizes[0] / 1024;   // 16384
    const int mblocks = Btot / BM;            // 128
    const int nblocks = 1024 / BHC;           // 16
    dim3 grid(mblocks * nblocks);             // 2048, m fastest
    dim3 block(256);
    hipLaunchKernelGGL(lstm_mfma_f16, grid, block, 0, stream,
                       X, Hprev, Cprev, Wih, Whh, bih, bhh, Out, Btot, mblocks);
}

// Round 3
// 641.261 us; speedup vs baseline: 11.1812x; 1.3729x over previous
//
#include <hip/hip_runtime.h>
#include <cstdint>
#include <cstddef>

// LSTM cell: g = [X|Hprev] @ [Wih|Whh]^T + b -> gates -> (h_new, c_new)
// Round 3: two-pass. Pass 1 converts all fp32 operands to fp16 in d_ws.
// Pass 2 is an m97-structure GEMM: 128m x 128n (4 gates x 32 h) x BK=32,
// global_load_lds width=16 direct-to-LDS, single-buffer 2-barrier K-loop,
// XOR-swizzled LDS chunks (conflict-free b128 frag reads), fused LDS-slab
// epilogue. Fallback to the round-2 inline-convert kernel if ws too small.

typedef _Float16 half8 __attribute__((ext_vector_type(8)));
typedef float f32x4 __attribute__((ext_vector_type(4)));

__device__ __forceinline__ float sigmoidf_(float x) { return 1.0f / (1.0f + __expf(-x)); }
__device__ __forceinline__ float tanh_fast(float x) { return 2.0f / (1.0f + __expf(-2.0f * x)) - 1.0f; }

__device__ __forceinline__ void gld16(const void* g, void* lds) {
    // 16B/lane async global->LDS; lds base must be wave-uniform (dest = base + lane*16)
    __builtin_amdgcn_global_load_lds((const __attribute__((address_space(1))) uint32_t*)g,
                                     (__attribute__((address_space(3))) uint32_t*)lds, 16, 0, 0);
}

// ---------------- pass 1: fp32 -> fp16 ----------------
__global__ __launch_bounds__(256)
void convert_to_f16(const float* __restrict__ X, const float* __restrict__ H,
                    const float* __restrict__ Wih, const float* __restrict__ Whh,
                    _Float16* __restrict__ ws, long nX, long nW)
{
    long e = ((long)blockIdx.x * 256 + threadIdx.x) * 8;
    long total = 2 * nX + 2 * nW;
    if (e >= total) return;
    const float* src; long off;
    if (e < nX)              { src = X;   off = e; }
    else if (e < 2 * nX)     { src = H;   off = e - nX; }
    else if (e < 2 * nX + nW){ src = Wih; off = e - 2 * nX; }
    else                     { src = Whh; off = e - 2 * nX - nW; }
    float4 a = *(const float4*)(src + off);
    float4 b = *(const float4*)(src + off + 4);
    half8 h;
    h[0]=(_Float16)a.x; h[1]=(_Float16)a.y; h[2]=(_Float16)a.z; h[3]=(_Float16)a.w;
    h[4]=(_Float16)b.x; h[5]=(_Float16)b.y; h[6]=(_Float16)b.z; h[7]=(_Float16)b.w;
    *(half8*)(ws + e) = h;
}

// ---------------- pass 2: MFMA GEMM + fused gates ----------------
__global__ __launch_bounds__(256, 4)
void lstm_mfma_v2(const _Float16* __restrict__ ws,   // Xh | Hh | Wih_h | Whh_h
                  const float* __restrict__ Cprev,
                  const float* __restrict__ bih, const float* __restrict__ bhh,
                  float* __restrict__ Out, int Btot, int mblocks)
{
    __shared__ alignas(16) char smem[16384];          // A tile 8KB | B tile 8KB; epilogue reuse
    float* Cl = (float*)smem;                         // [16][132] fp32 slab

    const long nX = (long)Btot * 1024;
    const long nW = 4096L * 1024;
    const _Float16* Xh = ws;
    const _Float16* Hh = ws + nX;
    const _Float16* Wi = ws + 2 * nX;
    const _Float16* Wh = ws + 2 * nX + nW;

    const int tid = threadIdx.x;
    const int w = tid >> 6, l = tid & 63;
    const int lr = l & 15, q = l >> 4;
    const int mh = w & 1, nh = w >> 1;

    const int bx   = blockIdx.x;
    const int m0   = (bx % mblocks) * 128;
    const int hblk = (bx / mblocks) * 32;

    // staging: issue j (0..1) x wave w covers LDS rows [(j*4+w)*16, +16) of a 128x32-half tile
    uint32_t gOffA[2], gOffB[2];
    void* ldsA[2]; void* ldsB[2];
    #pragma unroll
    for (int j = 0; j < 2; ++j) {
        int ubase = (j * 4 + w) * 1024;               // wave-uniform LDS byte base
        int off = ubase + l * 16;                     // this lane's LDS byte slot
        int r   = off >> 6;                           // tile row (64B rows)
        int cl_ = (off >> 4) & 3;                     // LDS k-chunk
        int c   = cl_ ^ ((r >> 1) & 3);               // global k-chunk (XOR swizzle)
        ldsA[j] = (void*)(smem + ubase);
        ldsB[j] = (void*)(smem + 8192 + ubase);
        gOffA[j] = (uint32_t)(m0 + r) * 1024u + (uint32_t)(c * 8);
        int g_ = r >> 5, hcol = hblk + (r & 31);      // B row -> gate, h-col
        gOffB[j] = (uint32_t)(g_ * 1024 + hcol) * 1024u + (uint32_t)(c * 8);
    }

    // fragment-read LDS byte offsets (swizzled chunk)
    const int sw = (lr >> 1) & 3;
    int aOff[4], bOff[4];
    #pragma unroll
    for (int t = 0; t < 4; ++t) {
        aOff[t] = ((mh * 64 + t * 16 + lr) * 32 + (q ^ sw) * 8) * 2;
        bOff[t] = 8192 + ((nh * 64 + t * 16 + lr) * 32 + (q ^ sw) * 8) * 2;
    }

    f32x4 acc[4][4];
    #pragma unroll
    for (int i = 0; i < 4; ++i)
        #pragma unroll
        for (int j = 0; j < 4; ++j)
            acc[i][j] = (f32x4){0.f, 0.f, 0.f, 0.f};

    for (int tile = 0; tile < 64; ++tile) {
        const _Float16* Ap = (tile < 32) ? Xh : Hh;
        const _Float16* Bp = (tile < 32) ? Wi : Wh;
        const uint32_t k0 = (uint32_t)(tile & 31) * 32u;
        gld16(Ap + gOffA[0] + k0, ldsA[0]);
        gld16(Ap + gOffA[1] + k0, ldsA[1]);
        gld16(Bp + gOffB[0] + k0, ldsB[0]);
        gld16(Bp + gOffB[1] + k0, ldsB[1]);
        __syncthreads();                              // drains vmcnt -> staging visible

        half8 af[4], bf[4];
        #pragma unroll
        for (int t = 0; t < 4; ++t) af[t] = *(const half8*)(smem + aOff[t]);
        #pragma unroll
        for (int t = 0; t < 4; ++t) bf[t] = *(const half8*)(smem + bOff[t]);
        #pragma unroll
        for (int mt = 0; mt < 4; ++mt)
            #pragma unroll
            for (int nt = 0; nt < 4; ++nt)
                acc[mt][nt] = __builtin_amdgcn_mfma_f32_16x16x32_f16(af[mt], bf[nt], acc[mt][nt], 0, 0, 0);
        __syncthreads();                              // compute done before next tile lands
    }

    // ---- epilogue: 8 slabs of 16m x 128n through LDS; thread owns (m, h) with all 4 gates ----
    const int h_l = tid & 31;
    const int h   = hblk + h_l;
    const int m_l = tid >> 5;                         // 0..7 (covers m_l and m_l+8)
    float bsum[4];
    #pragma unroll
    for (int g = 0; g < 4; ++g) bsum[g] = bih[g * 1024 + h] + bhh[g * 1024 + h];
    const long c_off = (long)Btot * 1024;

    for (int mt = 0; mt < 8; ++mt) {
        if ((mt >> 2) == mh) {                        // this wave owns slab mt
            const int mti = mt & 3;
            #pragma unroll
            for (int nt = 0; nt < 4; ++nt)
                #pragma unroll
                for (int r = 0; r < 4; ++r)
                    Cl[(q * 4 + r) * 132 + nh * 64 + nt * 16 + lr] = acc[mti][nt][r];
        }
        __syncthreads();
        #pragma unroll
        for (int mm = m_l; mm < 16; mm += 8) {
            float gi = Cl[mm * 132 +   0 + h_l] + bsum[0];
            float gf = Cl[mm * 132 +  32 + h_l] + bsum[1];
            float gc = Cl[mm * 132 +  64 + h_l] + bsum[2];
            float go = Cl[mm * 132 +  96 + h_l] + bsum[3];
            float ig = sigmoidf_(gi), fg = sigmoidf_(gf);
            float cd = tanh_fast(gc), og = sigmoidf_(go);
            const int m = m0 + mt * 16 + mm;
            const long idx = (long)m * 1024 + h;
            float c_new = Cprev[idx] * fg + ig * cd;
            Out[idx]         = tanh_fast(c_new) * og;
            Out[c_off + idx] = c_new;
        }
        __syncthreads();
    }
}

// ---------------- fallback (round-2 kernel): used only if ws too small ----------------
__global__ __launch_bounds__(256, 2)
void lstm_mfma_f16_fb(const float* __restrict__ X, const float* __restrict__ Hprev,
                      const float* __restrict__ Cprev,
                      const float* __restrict__ Wih, const float* __restrict__ Whh,
                      const float* __restrict__ bih, const float* __restrict__ bhh,
                      float* __restrict__ Out, int Btot, int mblocks)
{
    __shared__ alignas(16) _Float16 As[128][40];
    __shared__ alignas(16) _Float16 Bs[256][40];
    const int tid = threadIdx.x;
    const int w = tid >> 6, lane = tid & 63, lr = lane & 15, q = lane >> 4;
    const int bx = blockIdx.x, mblk = bx % mblocks, nblk = bx / mblocks;
    const int m0 = mblk * 128, hblk = nblk * 64;
    const int sr = tid >> 1, sc = tid & 1;
    f32x4 acc[8][4];
    #pragma unroll
    for (int mt = 0; mt < 8; ++mt)
        #pragma unroll
        for (int g = 0; g < 4; ++g) acc[mt][g] = (f32x4){0.f,0.f,0.f,0.f};
    float4 pa[4], pb0[4], pb1[4];
    const int rb1 = sr + 128;
    const size_t wrow0 = (size_t)((sr >> 6) * 1024 + hblk + (sr & 63)) * 1024;
    const size_t wrow1 = (size_t)((rb1 >> 6) * 1024 + hblk + (rb1 & 63)) * 1024;
    const size_t arow  = (size_t)(m0 + sr) * 1024;
    auto stage_load = [&](int tile) {
        const int phase = tile >> 5;
        const int k0 = (tile & 31) * 32 + sc * 16;
        const float* Ap = phase ? Hprev : X;
        const float* Wp = phase ? Whh : Wih;
        const float4* ap = (const float4*)(Ap + arow + k0);
        const float4* b0 = (const float4*)(Wp + wrow0 + k0);
        const float4* b1 = (const float4*)(Wp + wrow1 + k0);
        #pragma unroll
        for (int i = 0; i < 4; ++i) { pa[i] = ap[i]; pb0[i] = b0[i]; pb1[i] = b1[i]; }
    };
    auto pack8 = [](float4 a, float4 b) {
        half8 h;
        h[0]=(_Float16)a.x; h[1]=(_Float16)a.y; h[2]=(_Float16)a.z; h[3]=(_Float16)a.w;
        h[4]=(_Float16)b.x; h[5]=(_Float16)b.y; h[6]=(_Float16)b.z; h[7]=(_Float16)b.w;
        return h;
    };
    stage_load(0);
    for (int tile = 0; tile < 64; ++tile) {
        __syncthreads();
        *(half8*)&As[sr][sc*16]        = pack8(pa[0], pa[1]);
        *(half8*)&As[sr][sc*16+8]      = pack8(pa[2], pa[3]);
        *(half8*)&Bs[sr][sc*16]        = pack8(pb0[0], pb0[1]);
        *(half8*)&Bs[sr][sc*16+8]      = pack8(pb0[2], pb0[3]);
        *(half8*)&Bs[sr+128][sc*16]    = pack8(pb1[0], pb1[1]);
        *(half8*)&Bs[sr+128][sc*16+8]  = pack8(pb1[2], pb1[3]);
        __syncthreads();
        if (tile + 1 < 64) stage_load(tile + 1);
        half8 bf[4];
        #pragma unroll
        for (int g = 0; g < 4; ++g) bf[g] = *(const half8*)&Bs[g*64 + w*16 + lr][q*8];
        #pragma unroll
        for (int mt = 0; mt < 8; ++mt) {
            half8 a = *(const half8*)&As[mt*16 + lr][q*8];
            #pragma unroll
            for (int g = 0; g < 4; ++g)
                acc[mt][g] = __builtin_amdgcn_mfma_f32_16x16x32_f16(a, bf[g], acc[mt][g], 0, 0, 0);
        }
    }
    const int h = hblk + w * 16 + lr;
    float bs0 = bih[h] + bhh[h];
    float bs1 = bih[1024+h] + bhh[1024+h];
    float bs2 = bih[2048+h] + bhh[2048+h];
    float bs3 = bih[3072+h] + bhh[3072+h];
    const size_t c_off = (size_t)Btot * 1024;
    #pragma unroll
    for (int mt = 0; mt < 8; ++mt)
        #pragma unroll
        for (int r = 0; r < 4; ++r) {
            const int m = m0 + mt*16 + q*4 + r;
            const size_t idx = (size_t)m * 1024 + h;
            float gi = acc[mt][0][r]+bs0, gf = acc[mt][1][r]+bs1;
            float gc = acc[mt][2][r]+bs2, go = acc[mt][3][r]+bs3;
            float ig = sigmoidf_(gi), fg = sigmoidf_(gf);
            float cd = tanh_fast(gc), og = sigmoidf_(go);
            float c_new = Cprev[idx]*fg + ig*cd;
            Out[idx] = tanh_fast(c_new)*og;
            Out[c_off+idx] = c_new;
        }
}

extern "C" void kernel_launch(void* const* d_in, const int* in_sizes, int n_in,
                              void* d_out, int out_size, void* d_ws, size_t ws_size,
                              hipStream_t stream) {
    const float* X     = (const float*)d_in[0];
    const float* Hprev = (const float*)d_in[1];
    const float* Cprev = (const float*)d_in[2];
    const float* Wih   = (const float*)d_in[3];
    const float* Whh   = (const float*)d_in[4];
    const float* bih   = (const float*)d_in[5];
    const float* bhh   = (const float*)d_in[6];
    float* Out = (float*)d_out;

    const int Btot = in_sizes[0] / 1024;
    const long nX = (long)Btot * 1024, nW = 4096L * 1024;
    const size_t need = (size_t)(2 * nX + 2 * nW) * sizeof(_Float16);

    if (ws_size >= need) {
        _Float16* ws = (_Float16*)d_ws;
        const long total = 2 * nX + 2 * nW;
        const int cblocks = (int)((total / 8 + 255) / 256);
        hipLaunchKernelGGL(convert_to_f16, dim3(cblocks), dim3(256), 0, stream,
                           X, Hprev, Wih, Whh, ws, nX, nW);
        const int mblocks = Btot / 128;               // 128
        const int nblocks = 1024 / 32;                // 32
        hipLaunchKernelGGL(lstm_mfma_v2, dim3(mblocks * nblocks), dim3(256), 0, stream,
                           ws, Cprev, bih, bhh, Out, Btot, mblocks);
    } else {
        const int mblocks = Btot / 128;
        hipLaunchKernelGGL(lstm_mfma_f16_fb, dim3(mblocks * 16), dim3(256), 0, stream,
                           X, Hprev, Cprev, Wih, Whh, bih, bhh, Out, Btot, mblocks);
    }
}